// Round 10
// baseline (312.046 us; speedup 1.0000x reference)
//
#include <hip/hip_runtime.h>

#define N_NODES 65536
#define N_EDGES 1048576
#define IN_FEATS 128
#define N_HIDDEN 64
// padded CSR: 64 slots/node, split as 2 replicas x 32 slots. deg per replica ~Poisson(8);
// P(>32) ~ 1e-11 per (node,replica) -> safe.

static constexpr float F_EPS = 1e-12f;

// ---------------- GEMM body: C[64 rows x 64] = act(A @ W + b), 16KB LDS phases ----
template <int K, bool RELU, bool RN>
__device__ __forceinline__ void gemm_body(const float* __restrict__ A,
                                          const float* __restrict__ W,
                                          const float* __restrict__ bias,
                                          float* __restrict__ C,
                                          float* __restrict__ rn,
                                          int block64, int tid, float* Wl) {
  int lane = tid & 63;
  int wave = tid >> 6;
  float bv = bias[lane];
  int r0 = block64 * 64 + wave * 16;

  float a[16][K / 64];
#pragma unroll
  for (int r = 0; r < 16; ++r)
#pragma unroll
    for (int c = 0; c < K / 64; ++c)
      a[r][c] = A[(size_t)(r0 + r) * K + c * 64 + lane];

  float acc[16];
#pragma unroll
  for (int r = 0; r < 16; ++r) acc[r] = bv;

  const float4* W4 = reinterpret_cast<const float4*>(W);
  float4* Wl4 = reinterpret_cast<float4*>(Wl);

#pragma unroll
  for (int c = 0; c < K / 64; ++c) {
    __syncthreads();
#pragma unroll
    for (int i = tid; i < 64 * 16; i += 256) Wl4[i] = W4[c * 64 * 16 + i];
    __syncthreads();
#pragma unroll 8
    for (int kk = 0; kk < 64; ++kk) {
      float w = Wl[kk * 64 + lane];
#pragma unroll
      for (int r = 0; r < 16; ++r) {
        float av = __uint_as_float(
            __builtin_amdgcn_readlane(__float_as_uint(a[r][c]), kk));
        acc[r] = fmaf(av, w, acc[r]);
      }
    }
  }

#pragma unroll
  for (int r = 0; r < 16; ++r) {
    float v = acc[r];
    if (RELU) v = fmaxf(v, 0.0f);
    C[(size_t)(r0 + r) * 64 + lane] = v;
    if (RN) {
      float ss = v * v;
#pragma unroll
      for (int off = 32; off > 0; off >>= 1) ss += __shfl_xor(ss, off, 64);
      if (lane == 0) rn[r0 + r] = 1.0f / fmaxf(sqrtf(ss), F_EPS);
    }
  }
}

// ---------------- fused proj-GEMM + padded-CSR scatter (replicated counters) ------
// 5120 blocks: bb%5==4 -> gemm unit bb/5 (1024 units); else scatter unit bb/5*4+bb%5
// (4096 units x 256 edges, 1 edge/thread).
__global__ __launch_bounds__(256) void proj_scatter_k(
    const float* __restrict__ A, const float* __restrict__ W,
    const float* __restrict__ bias, float* __restrict__ C, float* __restrict__ rn,
    const int* __restrict__ src, const int* __restrict__ dst,
    int* __restrict__ deg2, int* __restrict__ csr) {
  __shared__ float Wl[64 * 64];
  int bb = blockIdx.x;
  int g = bb / 5;
  int r = bb % 5;
  if (r == 4) {
    gemm_body<IN_FEATS, true, true>(A, W, bias, C, rn, g, threadIdx.x, Wl);
  } else {
    int t = (g * 4 + r) * 256 + threadIdx.x;
    int d = dst[t];
    int s = src[t];
    int rep = t & 1;
    int p = atomicAdd(&deg2[rep * N_NODES + d], 1);
    if (p < 32) csr[(d << 6) + (rep << 5) + p] = s;
  }
}

// ---------------- standalone GEMM (cls) ----------------
template <int K, bool RELU, bool RN>
__global__ __launch_bounds__(256) void gemm64_k(const float* __restrict__ A,
                                                const float* __restrict__ W,
                                                const float* __restrict__ bias,
                                                float* __restrict__ C,
                                                float* __restrict__ rn) {
  __shared__ float Wl[64 * 64];
  gemm_body<K, RELU, RN>(A, W, bias, C, rn, blockIdx.x, threadIdx.x, Wl);
}

// ---------------- fused AGNN conv: wave-per-dst-node, 16 edges in flight ----------
// lane = 4*g + sl; group g in [0,16) handles edge (i+g); sublane sl in [0,4) owns
// float4s {sl, sl+4, sl+8, sl+12} of the 64-float row (full row per group).
// softmax without max-subtraction: |e| <= |beta|, exp is safe.
__global__ __launch_bounds__(256) void agnn_k(const float* __restrict__ X,
                                              const float* __restrict__ rn,
                                              const int* __restrict__ deg2,
                                              const int* __restrict__ csr,
                                              const float* __restrict__ betas, int layer,
                                              float* __restrict__ Y,
                                              float* __restrict__ rn_out) {
  int node = blockIdx.x * 4 + (threadIdx.x >> 6);
  int lane = threadIdx.x & 63;
  int sl = lane & 3;
  int g = lane >> 2;
  float beta = betas[layer];

  const float4* X4 = reinterpret_cast<const float4*>(X);
  float4 hd[4];
#pragma unroll
  for (int q = 0; q < 4; ++q) hd[q] = X4[(size_t)node * 16 + sl + 4 * q];
  float rnd = rn[node] * beta;

  int d0 = deg2[node];
  int d1 = deg2[N_NODES + node];
  d0 = d0 > 32 ? 32 : d0;
  d1 = d1 > 32 ? 32 : d1;
  int d = d0 + d1;
  int base = node << 6;

  float ssum = 0.0f;
  float4 acc[4];
#pragma unroll
  for (int q = 0; q < 4; ++q) acc[q] = make_float4(0.f, 0.f, 0.f, 0.f);

  // prologue prefetch: logical edge g
  bool act0 = (g < d);
  int slot0 = (g < d0) ? g : (g - d0 + 32);
  int s0 = act0 ? csr[base + slot0] : node;
  float4 hs0[4];
#pragma unroll
  for (int q = 0; q < 4; ++q) hs0[q] = X4[(size_t)s0 * 16 + sl + 4 * q];
  float rs0 = rn[s0];

  for (int i = 0; i < d; i += 16) {
    // prefetch next round while computing current
    int j1 = i + 16 + g;
    bool act1 = (j1 < d);
    int slot1 = (j1 < d0) ? j1 : (j1 - d0 + 32);
    int s1 = act1 ? csr[base + slot1] : node;
    float4 hs1[4];
#pragma unroll
    for (int q = 0; q < 4; ++q) hs1[q] = X4[(size_t)s1 * 16 + sl + 4 * q];
    float rs1 = rn[s1];

    // dot over this lane's 16 floats (two independent chains), reduce over 4 lanes
    float pa = hd[0].x * hs0[0].x;
    pa = fmaf(hd[0].y, hs0[0].y, pa);
    pa = fmaf(hd[0].z, hs0[0].z, pa);
    pa = fmaf(hd[0].w, hs0[0].w, pa);
    pa = fmaf(hd[1].x, hs0[1].x, pa);
    pa = fmaf(hd[1].y, hs0[1].y, pa);
    pa = fmaf(hd[1].z, hs0[1].z, pa);
    pa = fmaf(hd[1].w, hs0[1].w, pa);
    float pb = hd[2].x * hs0[2].x;
    pb = fmaf(hd[2].y, hs0[2].y, pb);
    pb = fmaf(hd[2].z, hs0[2].z, pb);
    pb = fmaf(hd[2].w, hs0[2].w, pb);
    pb = fmaf(hd[3].x, hs0[3].x, pb);
    pb = fmaf(hd[3].y, hs0[3].y, pb);
    pb = fmaf(hd[3].z, hs0[3].z, pb);
    pb = fmaf(hd[3].w, hs0[3].w, pb);
    float p = pa + pb;
    p += __shfl_xor(p, 1, 64);
    p += __shfl_xor(p, 2, 64);
    float ex = act0 ? __expf(p * rnd * rs0) : 0.0f;
    ssum += ex;
#pragma unroll
    for (int q = 0; q < 4; ++q) {
      acc[q].x = fmaf(ex, hs0[q].x, acc[q].x);
      acc[q].y = fmaf(ex, hs0[q].y, acc[q].y);
      acc[q].z = fmaf(ex, hs0[q].z, acc[q].z);
      acc[q].w = fmaf(ex, hs0[q].w, acc[q].w);
    }

#pragma unroll
    for (int q = 0; q < 4; ++q) hs0[q] = hs1[q];
    rs0 = rs1;
    act0 = act1;
  }

  // combine the 16 groups: butterfly over offs 4,8,16,32 (allreduce)
#pragma unroll
  for (int off = 4; off < 64; off <<= 1) {
    ssum += __shfl_xor(ssum, off, 64);
#pragma unroll
    for (int q = 0; q < 4; ++q) {
      acc[q].x += __shfl_xor(acc[q].x, off, 64);
      acc[q].y += __shfl_xor(acc[q].y, off, 64);
      acc[q].z += __shfl_xor(acc[q].z, off, 64);
      acc[q].w += __shfl_xor(acc[q].w, off, 64);
    }
  }

  float inv = (ssum > 0.0f) ? (1.0f / ssum) : 0.0f;
#pragma unroll
  for (int q = 0; q < 4; ++q) {
    acc[q].x *= inv; acc[q].y *= inv; acc[q].z *= inv; acc[q].w *= inv;
  }

  if (g == 0) {
    float4* Y4 = reinterpret_cast<float4*>(Y);
#pragma unroll
    for (int q = 0; q < 4; ++q) Y4[(size_t)node * 16 + sl + 4 * q] = acc[q];
  }

  // fused rnorm of the output (for the next layer)
  float ss = 0.0f;
#pragma unroll
  for (int q = 0; q < 4; ++q)
    ss += acc[q].x * acc[q].x + acc[q].y * acc[q].y +
          acc[q].z * acc[q].z + acc[q].w * acc[q].w;
  ss += __shfl_xor(ss, 1, 64);
  ss += __shfl_xor(ss, 2, 64);
  if (lane == 0) rn_out[node] = 1.0f / fmaxf(sqrtf(ss), F_EPS);
}

// ---------------- launch ----------------
extern "C" void kernel_launch(void* const* d_in, const int* in_sizes, int n_in,
                              void* d_out, int out_size, void* d_ws, size_t ws_size,
                              hipStream_t stream) {
  const float* features = (const float*)d_in[0];
  const int* src = (const int*)d_in[1];
  const int* dst = (const int*)d_in[2];
  const float* W1 = (const float*)d_in[3];
  const float* b1 = (const float*)d_in[4];
  const float* W2 = (const float*)d_in[5];
  const float* b2 = (const float*)d_in[6];
  const float* betas = (const float*)d_in[7];
  float* out = (float*)d_out;

  char* ws = (char*)d_ws;
  size_t off = 0;
  auto alloc = [&](size_t bytes) {
    void* p = ws + off;
    off += (bytes + 255) & ~255UL;
    return p;
  };
  float* hA = (float*)alloc((size_t)N_NODES * 64 * 4);
  float* hB = (float*)alloc((size_t)N_NODES * 64 * 4);
  float* rnA = (float*)alloc((size_t)N_NODES * 4);
  float* rnB = (float*)alloc((size_t)N_NODES * 4);
  int* deg2 = (int*)alloc((size_t)2 * N_NODES * 4);
  int* csr = (int*)alloc((size_t)N_NODES * 64 * 4);

  hipMemsetAsync(deg2, 0, (size_t)2 * N_NODES * 4, stream);

  // fused: proj gemm (1024 units) + CSR scatter (4096 units), interleaved 1:4
  proj_scatter_k<<<5120, 256, 0, stream>>>(features, W1, b1, hA, rnA,
                                           src, dst, deg2, csr);

  // layer 0: hA -> hB (emits rnB)
  agnn_k<<<N_NODES / 4, 256, 0, stream>>>(hA, rnA, deg2, csr, betas, 0, hB, rnB);

  // layer 1: hB -> hA (emits rnA, unused)
  agnn_k<<<N_NODES / 4, 256, 0, stream>>>(hB, rnB, deg2, csr, betas, 1, hA, rnA);

  // cls: out = hA @ W2 + b2
  gemm64_k<N_HIDDEN, false, false><<<N_NODES / 64, 256, 0, stream>>>(hA, W2, b2, out, nullptr);
}